// Round 1
// baseline (388.231 us; speedup 1.0000x reference)
//
#include <hip/hip_runtime.h>

#define H 256
#define B 4
#define N 64
#define T 256
#define L 5
#define TOPK 8

__device__ __forceinline__ float wave_reduce_sum(float v) {
    #pragma unroll
    for (int off = 32; off > 0; off >>= 1) v += __shfl_xor(v, off, 64);
    return v;
}

// ---------------------------------------------------------------------------
// K0: classify peer_mask storage layout (bool bytes / int32 / float32) and
// expand to int[256]. 256 threads, 1 block.
// ---------------------------------------------------------------------------
__global__ __launch_bounds__(256) void mask_expand_kernel(const unsigned char* __restrict__ raw,
                                                          int* __restrict__ out) {
    __shared__ int nzOff, byteBad, intBad;
    int tid = threadIdx.x;
    if (tid == 0) { nzOff = 0; byteBad = 0; intBad = 0; }
    __syncthreads();
    unsigned char c = raw[tid];
    if ((tid & 3) && c) atomicOr(&nzOff, 1);
    if (c > 1) atomicOr(&byteBad, 1);
    if (tid < 64) {  // first 256 bytes — in-bounds for every candidate layout
        unsigned int iv = ((const unsigned int*)raw)[tid];
        if (iv > 1u) atomicOr(&intBad, 1);
    }
    __syncthreads();
    int v;
    if (nzOff && !byteBad)  v = (raw[tid] != 0);                       // 1-byte bools
    else if (!intBad)       v = (((const unsigned int*)raw)[tid] != 0); // int32 0/1
    else                    v = (((const float*)raw)[tid] != 0.0f);     // float32 0/1
    out[tid] = v;
}

// ---------------------------------------------------------------------------
// fill logits with -inf (entries with t-lag<0 or masked peers keep it)
// ---------------------------------------------------------------------------
__global__ void fill_neginf_kernel(float* __restrict__ p, int n) {
    int i = blockIdx.x * blockDim.x + threadIdx.x;
    if (i < n) p[i] = -__builtin_inff();
}

// ---------------------------------------------------------------------------
// Generic fp32 GEMM: C[M,256] = A[M,256] @ W[256,256]^T + epilogue
// EPI 0: + bias
// EPI 1: + rowscale[m]*bias   (cs_y with sum-of-weights-scaled bv)
// EPI 2: elu(+ bias)
// EPI 3: + bias + resid
// 64x64 tile / block of 256 threads, 4x4 acc per thread. M % 64 == 0.
// ---------------------------------------------------------------------------
template <int EPI>
__global__ __launch_bounds__(256) void gemm_atw_kernel(
    const float* __restrict__ A, const float* __restrict__ W,
    const float* __restrict__ bias, const float* __restrict__ rowscale,
    const float* __restrict__ resid, float* __restrict__ C, int M) {
    __shared__ float As[16][68];
    __shared__ float Ws[16][68];
    int tid = threadIdx.x;
    int tx = tid & 15, ty = tid >> 4;
    int m0 = (blockIdx.x >> 2) * 64;
    int j0 = (blockIdx.x & 3) * 64;
    int lm = tid >> 2;            // 0..63
    int lk = (tid & 3) << 2;      // 0,4,8,12
    float acc[4][4] = {};
    const float* Arow = A + (size_t)(m0 + lm) * H + lk;
    const float* Wrow = W + (size_t)(j0 + lm) * H + lk;
    for (int kc = 0; kc < H; kc += 16) {
        float4 av = *(const float4*)(Arow + kc);
        float4 wv = *(const float4*)(Wrow + kc);
        As[lk + 0][lm] = av.x; As[lk + 1][lm] = av.y; As[lk + 2][lm] = av.z; As[lk + 3][lm] = av.w;
        Ws[lk + 0][lm] = wv.x; Ws[lk + 1][lm] = wv.y; Ws[lk + 2][lm] = wv.z; Ws[lk + 3][lm] = wv.w;
        __syncthreads();
        #pragma unroll
        for (int kk = 0; kk < 16; kk++) {
            float4 a  = *(const float4*)&As[kk][ty * 4];
            float4 bb = *(const float4*)&Ws[kk][tx * 4];
            float avv[4] = {a.x, a.y, a.z, a.w};
            float bvv[4] = {bb.x, bb.y, bb.z, bb.w};
            #pragma unroll
            for (int i = 0; i < 4; i++)
                #pragma unroll
                for (int j = 0; j < 4; j++)
                    acc[i][j] = fmaf(avv[i], bvv[j], acc[i][j]);
        }
        __syncthreads();
    }
    #pragma unroll
    for (int i = 0; i < 4; i++) {
        int m = m0 + ty * 4 + i;
        int jj = j0 + tx * 4;
        float bs = (EPI == 1) ? rowscale[m] : 1.0f;
        float ov[4];
        #pragma unroll
        for (int j = 0; j < 4; j++) {
            float x = acc[i][j] + bias[jj + j] * bs;
            if (EPI == 2) x = (x > 0.0f) ? x : expm1f(x);
            if (EPI == 3) x += resid[(size_t)m * H + jj + j];
            ov[j] = x;
        }
        float4 o = {ov[0], ov[1], ov[2], ov[3]};
        *(float4*)&C[(size_t)m * H + jj] = o;
    }
}

// ---------------------------------------------------------------------------
// Fused: K-tile = peer_h[b,n,t0:t0+64,:] @ wk^T + bk (into LDS, never HBM),
// then logits[b,t,n,l] = dot(Q[b,t], Ktile[t-lag_l-t0]) / 16.
// One block per (b, n, t-tile of 64). Masked peers exit early (logits stay -inf).
// ---------------------------------------------------------------------------
__global__ __launch_bounds__(256) void peer_logits_kernel(
    const float* __restrict__ peer_h, const float* __restrict__ wk,
    const float* __restrict__ bk, const float* __restrict__ Q,
    const int* __restrict__ maskI, float* __restrict__ logits) {
    const int lags[L] = {1, 5, 10, 21, 30};
    int bi = blockIdx.x;
    int tt = bi & 3;
    int n  = (bi >> 2) & 63;
    int b  = bi >> 8;
    if (!maskI[b * N + n]) return;
    int t0 = tt * 64;
    __shared__ float As[16][68];
    __shared__ float Ws[16][68];
    __shared__ float Kt[64][260];   // 66.6 KB; total LDS ~75 KB -> 2 blocks/CU
    int tid = threadIdx.x;
    int tx = tid & 15, ty = tid >> 4;
    int lm = tid >> 2, lk = (tid & 3) << 2;
    const float* Abase = peer_h + ((size_t)(b * N + n) * T + t0) * H;
    for (int jt = 0; jt < 4; jt++) {
        int j0 = jt * 64;
        float acc[4][4] = {};
        for (int kc = 0; kc < H; kc += 16) {
            float4 av = *(const float4*)(Abase + (size_t)lm * H + kc + lk);
            float4 wv = *(const float4*)(wk + (size_t)(j0 + lm) * H + kc + lk);
            As[lk + 0][lm] = av.x; As[lk + 1][lm] = av.y; As[lk + 2][lm] = av.z; As[lk + 3][lm] = av.w;
            Ws[lk + 0][lm] = wv.x; Ws[lk + 1][lm] = wv.y; Ws[lk + 2][lm] = wv.z; Ws[lk + 3][lm] = wv.w;
            __syncthreads();
            #pragma unroll
            for (int kk = 0; kk < 16; kk++) {
                float4 a  = *(const float4*)&As[kk][ty * 4];
                float4 bb = *(const float4*)&Ws[kk][tx * 4];
                float avv[4] = {a.x, a.y, a.z, a.w};
                float bvv[4] = {bb.x, bb.y, bb.z, bb.w};
                #pragma unroll
                for (int i = 0; i < 4; i++)
                    #pragma unroll
                    for (int j = 0; j < 4; j++)
                        acc[i][j] = fmaf(avv[i], bvv[j], acc[i][j]);
            }
            __syncthreads();
        }
        #pragma unroll
        for (int i = 0; i < 4; i++)
            #pragma unroll
            for (int j = 0; j < 4; j++)
                Kt[ty * 4 + i][j0 + tx * 4 + j] = acc[i][j] + bk[j0 + tx * 4 + j];
        // Kt not read until after the barrier below; As/Ws reads all precede
        // the final __syncthreads of the kc loop.
    }
    __syncthreads();
    // Stage B: 320 dot products (64 rows x 5 lags), one wave each.
    int wave = tid >> 6, lane = tid & 63;
    for (int task = wave; task < 64 * L; task += 4) {
        int l = task % L;
        int r = task / L;
        int t = t0 + r + lags[l];
        if (t >= T) continue;
        const float* qrow = Q + ((size_t)b * T + t) * H;
        float s = 0.0f;
        #pragma unroll
        for (int i = 0; i < 4; i++)
            s = fmaf(Kt[r][lane + 64 * i], qrow[lane + 64 * i], s);
        s = wave_reduce_sum(s);
        if (lane == 0)
            logits[(((size_t)b * T + t) * N + n) * L + l] = s * 0.0625f;
    }
}

// ---------------------------------------------------------------------------
// Per (b,t): top-8 of 320 logits (ties -> lower index, matching lax.top_k),
// softmax over finite entries, then u = sum_k w_k * peer_h[row_k],
// sw = 1 if any finite else 0 (scales bv downstream).
// ---------------------------------------------------------------------------
__global__ __launch_bounds__(256) void topk_gather_kernel(
    const float* __restrict__ logits, const float* __restrict__ peer_h,
    float* __restrict__ u, float* __restrict__ sw) {
    const int lags[L] = {1, 5, 10, 21, 30};
    int row = blockIdx.x;            // b*T + t
    int b = row >> 8, t = row & 255;
    int tid = threadIdx.x;
    __shared__ float wS[TOPK];
    __shared__ int idxS[TOPK];
    __shared__ float swS;
    if (tid < 64) {                  // wave 0 does selection in-register
        int lane = tid;
        const float* lrow = logits + (size_t)row * (N * L);
        float v[5];
        #pragma unroll
        for (int i = 0; i < 5; i++) v[i] = lrow[lane + 64 * i];
        float tv[TOPK]; int tix[TOPK];
        for (int k = 0; k < TOPK; k++) {
            float bv = v[0]; int bidx = lane;
            #pragma unroll
            for (int i = 1; i < 5; i++) {
                if (v[i] > bv) { bv = v[i]; bidx = lane + 64 * i; }  // strict > keeps lower idx on tie
            }
            #pragma unroll
            for (int off = 32; off > 0; off >>= 1) {
                float ov = __shfl_xor(bv, off, 64);
                int   oi = __shfl_xor(bidx, off, 64);
                if (ov > bv || (ov == bv && oi < bidx)) { bv = ov; bidx = oi; }
            }
            tv[k] = bv; tix[k] = bidx;
            if ((bidx & 63) == lane) v[bidx >> 6] = -__builtin_inff();  // consume
        }
        if (lane == 0) {
            float m = -__builtin_inff();
            for (int k = 0; k < TOPK; k++)
                if (tv[k] > -__builtin_inff()) m = fmaxf(m, tv[k]);
            float den = 0.0f, w[TOPK];
            for (int k = 0; k < TOPK; k++) {
                w[k] = (tv[k] > -__builtin_inff()) ? expf(tv[k] - m) : 0.0f;
                den += w[k];
            }
            float inv = (den > 0.0f) ? 1.0f / den : 0.0f;
            for (int k = 0; k < TOPK; k++) { wS[k] = w[k] * inv; idxS[k] = tix[k]; }
            swS = (den > 0.0f) ? 1.0f : 0.0f;
        }
    }
    __syncthreads();
    float acc = 0.0f;
    #pragma unroll
    for (int k = 0; k < TOPK; k++) {
        float w = wS[k];
        if (w > 0.0f) {
            int idx = idxS[k];
            int n = idx / L, l = idx % L;
            int tp = t - lags[l];
            acc += w * peer_h[(((size_t)(b * N + n)) * T + tp) * H + tid];
        }
    }
    u[(size_t)row * H + tid] = acc;
    if (tid == 0) sw[row] = swS;
}

// ---------------------------------------------------------------------------
// Row LayerNorm (population variance), out = (y-mu)*rsqrt(var+eps)*gamma+beta
// ---------------------------------------------------------------------------
__global__ __launch_bounds__(256) void layernorm_kernel(
    const float* __restrict__ y, const float* __restrict__ gamma,
    const float* __restrict__ beta, float* __restrict__ out) {
    int row = blockIdx.x, tid = threadIdx.x;
    int wave = tid >> 6, lane = tid & 63;
    __shared__ float r1[4], r2[4];
    float v = y[(size_t)row * H + tid];
    float s = wave_reduce_sum(v);
    if (lane == 0) r1[wave] = s;
    __syncthreads();
    float mu = (r1[0] + r1[1] + r1[2] + r1[3]) * (1.0f / H);
    float d = v - mu;
    float sq = wave_reduce_sum(d * d);
    if (lane == 0) r2[wave] = sq;
    __syncthreads();
    float var = (r2[0] + r2[1] + r2[2] + r2[3]) * (1.0f / H);
    out[(size_t)row * H + tid] = d * rsqrtf(var + 1e-5f) * gamma[tid] + beta[tid];
}

// ---------------------------------------------------------------------------
extern "C" void kernel_launch(void* const* d_in, const int* in_sizes, int n_in,
                              void* d_out, int out_size, void* d_ws, size_t ws_size,
                              hipStream_t stream) {
    const float* target_h = (const float*)d_in[0];
    const float* peer_h   = (const float*)d_in[1];
    const unsigned char* peer_mask = (const unsigned char*)d_in[2];
    const float* wq = (const float*)d_in[3];
    const float* bq = (const float*)d_in[4];
    const float* wk = (const float*)d_in[5];
    const float* bk = (const float*)d_in[6];
    const float* wv = (const float*)d_in[7];
    const float* bv = (const float*)d_in[8];
    const float* w1 = (const float*)d_in[9];
    const float* b1 = (const float*)d_in[10];
    const float* w2 = (const float*)d_in[11];
    const float* b2 = (const float*)d_in[12];
    const float* gamma = (const float*)d_in[13];
    const float* beta  = (const float*)d_in[14];
    float* out = (float*)d_out;

    char* ws = (char*)d_ws;
    size_t off = 0;
    auto wsa = [&](size_t bytes) -> void* {
        void* p = ws + off;
        off += (bytes + 255) & ~(size_t)255;
        return p;
    };
    int*   maskI  = (int*)wsa(B * N * sizeof(int));
    float* Q      = (float*)wsa((size_t)B * T * H * 4);
    float* logits = (float*)wsa((size_t)B * T * N * L * 4);
    float* u      = (float*)wsa((size_t)B * T * H * 4);
    float* sw     = (float*)wsa((size_t)B * T * 4);
    float* csy    = (float*)wsa((size_t)B * T * H * 4);
    float* h1     = (float*)wsa((size_t)B * T * H * 4);
    float* yv     = (float*)wsa((size_t)B * T * H * 4);

    mask_expand_kernel<<<1, 256, 0, stream>>>(peer_mask, maskI);
    gemm_atw_kernel<0><<<(B * T / 64) * 4, 256, 0, stream>>>(target_h, wq, bq, nullptr, nullptr, Q, B * T);
    int nl = B * T * N * L;
    fill_neginf_kernel<<<(nl + 255) / 256, 256, 0, stream>>>(logits, nl);
    peer_logits_kernel<<<B * N * (T / 64), 256, 0, stream>>>(peer_h, wk, bk, Q, maskI, logits);
    topk_gather_kernel<<<B * T, 256, 0, stream>>>(logits, peer_h, u, sw);
    gemm_atw_kernel<1><<<(B * T / 64) * 4, 256, 0, stream>>>(u, wv, bv, sw, nullptr, csy, B * T);
    gemm_atw_kernel<2><<<(B * T / 64) * 4, 256, 0, stream>>>(csy, w1, b1, nullptr, nullptr, h1, B * T);
    gemm_atw_kernel<3><<<(B * T / 64) * 4, 256, 0, stream>>>(h1, w2, b2, nullptr, csy, yv, B * T);
    layernorm_kernel<<<B * T, 256, 0, stream>>>(yv, gamma, beta, out);
}

// Round 2
// 251.854 us; speedup vs baseline: 1.5415x; 1.5415x over previous
//
#include <hip/hip_runtime.h>

#define H 256
#define B 4
#define N 64
#define T 256
#define L 5
#define TOPK 8

__device__ __forceinline__ float wave_reduce_sum(float v) {
    #pragma unroll
    for (int off = 32; off > 0; off >>= 1) v += __shfl_xor(v, off, 64);
    return v;
}

// ---------------------------------------------------------------------------
// Generic fp32 64x64-tile GEMM body. C[M,256] = op(A) @ op(W) + epilogue.
// AT=0: A rows are M       (C[m,j] uses A[m,k])
// AT=1: A transposed       (C[m,j] uses A[k,m])
// WT=1: C = A @ W^T        (uses W[j,k])
// WT=0: C = A @ W          (uses W[k,j])
// EPI 0: +bias   1: +rowscale[m]*bias   2: elu(+bias)   3: +bias+resid   4: raw
// ---------------------------------------------------------------------------
template <int AT, int WT, int EPI>
__device__ __forceinline__ void gemm_body(
    const float* __restrict__ A, const float* __restrict__ W,
    const float* __restrict__ bias, const float* __restrict__ rowscale,
    const float* __restrict__ resid, float* __restrict__ C,
    int m0, int j0) {
    __shared__ float As[16][72];
    __shared__ float Ws[16][72];
    int tid = threadIdx.x;
    int tx = tid & 15, ty = tid >> 4;
    int lm = tid >> 2;            // 0..63
    int lk = (tid & 3) << 2;      // 0,4,8,12
    int kk16 = tid >> 4;          // 0..15
    int c4 = (tid & 15) << 2;     // 0..60
    float acc[4][4] = {};
    for (int kc = 0; kc < H; kc += 16) {
        if (AT == 0) {
            float4 av = *(const float4*)(A + (size_t)(m0 + lm) * H + kc + lk);
            As[lk + 0][lm] = av.x; As[lk + 1][lm] = av.y;
            As[lk + 2][lm] = av.z; As[lk + 3][lm] = av.w;
        } else {
            float4 av = *(const float4*)(A + (size_t)(kc + kk16) * H + m0 + c4);
            *(float4*)&As[kk16][c4] = av;
        }
        if (WT == 1) {
            float4 wv = *(const float4*)(W + (size_t)(j0 + lm) * H + kc + lk);
            Ws[lk + 0][lm] = wv.x; Ws[lk + 1][lm] = wv.y;
            Ws[lk + 2][lm] = wv.z; Ws[lk + 3][lm] = wv.w;
        } else {
            float4 wv = *(const float4*)(W + (size_t)(kc + kk16) * H + j0 + c4);
            *(float4*)&Ws[kk16][c4] = wv;
        }
        __syncthreads();
        #pragma unroll
        for (int kk = 0; kk < 16; kk++) {
            float4 a  = *(const float4*)&As[kk][ty * 4];
            float4 bb = *(const float4*)&Ws[kk][tx * 4];
            float avv[4] = {a.x, a.y, a.z, a.w};
            float bvv[4] = {bb.x, bb.y, bb.z, bb.w};
            #pragma unroll
            for (int i = 0; i < 4; i++)
                #pragma unroll
                for (int j = 0; j < 4; j++)
                    acc[i][j] = fmaf(avv[i], bvv[j], acc[i][j]);
        }
        __syncthreads();
    }
    #pragma unroll
    for (int i = 0; i < 4; i++) {
        int m = m0 + ty * 4 + i;
        int jj = j0 + tx * 4;
        float bs = (EPI == 1) ? rowscale[m] : 1.0f;
        float ov[4];
        #pragma unroll
        for (int j = 0; j < 4; j++) {
            float x = acc[i][j];
            if (EPI != 4) x += bias[jj + j] * bs;
            if (EPI == 2) x = (x > 0.0f) ? x : expm1f(x);
            if (EPI == 3) x += resid[(size_t)m * H + jj + j];
            ov[j] = x;
        }
        float4 o = {ov[0], ov[1], ov[2], ov[3]};
        *(float4*)&C[(size_t)m * H + jj] = o;
    }
}

template <int AT, int WT, int EPI>
__global__ __launch_bounds__(256) void gemm_kernel(
    const float* __restrict__ A, const float* __restrict__ W,
    const float* __restrict__ bias, const float* __restrict__ rowscale,
    const float* __restrict__ resid, float* __restrict__ C) {
    int m0 = (blockIdx.x >> 2) * 64;
    int j0 = (blockIdx.x & 3) * 64;
    gemm_body<AT, WT, EPI>(A, W, bias, rowscale, resid, C, m0, j0);
}

// ---------------------------------------------------------------------------
// Prep: blocks 0-15 compute Wqk = wq^T @ wk (Wqk[a,h] = sum_j wq[j,a] wk[j,h]).
// Block 16: classify peer_mask layout -> maskI, and cqk[h] = sum_j bq[j] wk[j,h].
// ---------------------------------------------------------------------------
__global__ __launch_bounds__(256) void prep_kernel(
    const float* __restrict__ wq, const float* __restrict__ wk,
    const float* __restrict__ bq, const unsigned char* __restrict__ mask_raw,
    float* __restrict__ Wqk, float* __restrict__ cqk, int* __restrict__ maskI) {
    if (blockIdx.x < 16) {
        int m0 = (blockIdx.x >> 2) * 64;
        int j0 = (blockIdx.x & 3) * 64;
        gemm_body<1, 0, 4>(wq, wk, nullptr, nullptr, nullptr, Wqk, m0, j0);
        return;
    }
    // --- mask classification (bool bytes / int32 / float32) ---
    __shared__ int nzOff, byteBad, intBad;
    int tid = threadIdx.x;
    if (tid == 0) { nzOff = 0; byteBad = 0; intBad = 0; }
    __syncthreads();
    unsigned char c = mask_raw[tid];
    if ((tid & 3) && c) atomicOr(&nzOff, 1);
    if (c > 1) atomicOr(&byteBad, 1);
    if (tid < 64) {
        unsigned int iv = ((const unsigned int*)mask_raw)[tid];
        if (iv > 1u) atomicOr(&intBad, 1);
    }
    __syncthreads();
    int v;
    if (nzOff && !byteBad)  v = (mask_raw[tid] != 0);
    else if (!intBad)       v = (((const unsigned int*)mask_raw)[tid] != 0);
    else                    v = (((const float*)mask_raw)[tid] != 0.0f);
    maskI[tid] = v;
    // --- cqk ---
    float s = 0.0f;
    #pragma unroll 8
    for (int k = 0; k < H; k++) s = fmaf(bq[k], wk[(size_t)k * H + tid], s);
    cqk[tid] = s;
}

// ---------------------------------------------------------------------------
// logits[b][n][t][l] = dot(Qk[b,t], peer_h[b,n,t-lag_l]) / 16   (or -inf).
// Block = (b, n, sec); sec owns t' in [64*sec, 64*sec+64). Each logits entry
// written exactly once (sec 0 also writes the 67 entries with t < lag_l),
// so no barriers / fill pass needed.
// ---------------------------------------------------------------------------
__global__ __launch_bounds__(256) void logits_dot_kernel(
    const float* __restrict__ Qk, const float* __restrict__ peer_h,
    const int* __restrict__ maskI, float* __restrict__ logits) {
    const int lags[L] = {1, 5, 10, 21, 30};
    int bi = blockIdx.x;
    int sec = bi & 3;
    int n = (bi >> 2) & 63;
    int b = bi >> 8;
    int tid = threadIdx.x, wave = tid >> 6, lane = tid & 63;
    float* lbase = logits + (size_t)(b * N + n) * T * L;
    bool masked = (maskI[b * N + n] == 0);
    if (sec == 0) {
        const int cum[6] = {0, 1, 6, 16, 37, 67};   // lag prefix sums
        if (tid < 67) {
            int l = 0;
            while (tid >= cum[l + 1]) l++;
            int t = tid - cum[l];
            lbase[t * L + l] = -__builtin_inff();
        }
    }
    int r0 = sec * 64;
    const float* prow = peer_h + (size_t)(b * N + n) * T * H;
    const float* qkb = Qk + (size_t)b * T * H;
    if (masked) {
        for (int tp = r0 + wave; tp < r0 + 64; tp += 4) {
            if (lane < L) {
                int t = tp + lags[lane];
                if (t < T) lbase[t * L + lane] = -__builtin_inff();
            }
        }
        return;
    }
    for (int tp = r0 + wave; tp < r0 + 64; tp += 4) {
        float4 p = *(const float4*)(prow + (size_t)tp * H + 4 * lane);
        #pragma unroll
        for (int li = 0; li < L; li++) {
            int t = tp + lags[li];
            if (t < T) {
                float4 q = *(const float4*)(qkb + (size_t)t * H + 4 * lane);
                float s = fmaf(p.x, q.x, fmaf(p.y, q.y, fmaf(p.z, q.z, p.w * q.w)));
                s = wave_reduce_sum(s);
                if (lane == 0) lbase[t * L + li] = s * 0.0625f;
            }
        }
    }
}

// ---------------------------------------------------------------------------
// Per (b,t): top-8 of 320 logits (ties -> lower flat index n*L+l), softmax
// over finite entries, u = sum_k w_k * peer_h[row_k], sw = any-finite flag.
// ---------------------------------------------------------------------------
__global__ __launch_bounds__(256) void topk_gather_kernel(
    const float* __restrict__ logits, const float* __restrict__ peer_h,
    float* __restrict__ u, float* __restrict__ sw) {
    const int lags[L] = {1, 5, 10, 21, 30};
    int row = blockIdx.x;            // b*T + t
    int b = row >> 8, t = row & 255;
    int tid = threadIdx.x;
    __shared__ float wS[TOPK];
    __shared__ int idxS[TOPK];
    __shared__ float swS;
    if (tid < 64) {
        int lane = tid;
        float v[5];
        #pragma unroll
        for (int i = 0; i < 5; i++) {
            int f = lane + 64 * i;          // flat index 0..319
            int nn = f / 5, ll = f % 5;
            v[i] = logits[((size_t)(b * N + nn) * T + t) * L + ll];
        }
        float tv[TOPK]; int tix[TOPK];
        for (int k = 0; k < TOPK; k++) {
            float bv = v[0]; int bidx = lane;
            #pragma unroll
            for (int i = 1; i < 5; i++) {
                if (v[i] > bv) { bv = v[i]; bidx = lane + 64 * i; }
            }
            #pragma unroll
            for (int off = 32; off > 0; off >>= 1) {
                float ov = __shfl_xor(bv, off, 64);
                int   oi = __shfl_xor(bidx, off, 64);
                if (ov > bv || (ov == bv && oi < bidx)) { bv = ov; bidx = oi; }
            }
            tv[k] = bv; tix[k] = bidx;
            if ((bidx & 63) == lane) v[bidx >> 6] = -__builtin_inff();
        }
        if (lane == 0) {
            float m = -__builtin_inff();
            for (int k = 0; k < TOPK; k++)
                if (tv[k] > -__builtin_inff()) m = fmaxf(m, tv[k]);
            float den = 0.0f, w[TOPK];
            for (int k = 0; k < TOPK; k++) {
                w[k] = (tv[k] > -__builtin_inff()) ? expf(tv[k] - m) : 0.0f;
                den += w[k];
            }
            float inv = (den > 0.0f) ? 1.0f / den : 0.0f;
            for (int k = 0; k < TOPK; k++) { wS[k] = w[k] * inv; idxS[k] = tix[k]; }
            swS = (den > 0.0f) ? 1.0f : 0.0f;
        }
    }
    __syncthreads();
    float acc = 0.0f;
    #pragma unroll
    for (int k = 0; k < TOPK; k++) {
        float w = wS[k];
        if (w > 0.0f) {
            int idx = idxS[k];
            int n = idx / L, l = idx % L;
            int tp = t - lags[l];
            acc += w * peer_h[(((size_t)(b * N + n)) * T + tp) * H + tid];
        }
    }
    u[(size_t)row * H + tid] = acc;
    if (tid == 0) sw[row] = swS;
}

// ---------------------------------------------------------------------------
__global__ __launch_bounds__(256) void layernorm_kernel(
    const float* __restrict__ y, const float* __restrict__ gamma,
    const float* __restrict__ beta, float* __restrict__ out) {
    int row = blockIdx.x, tid = threadIdx.x;
    int wave = tid >> 6, lane = tid & 63;
    __shared__ float r1[4], r2[4];
    float v = y[(size_t)row * H + tid];
    float s = wave_reduce_sum(v);
    if (lane == 0) r1[wave] = s;
    __syncthreads();
    float mu = (r1[0] + r1[1] + r1[2] + r1[3]) * (1.0f / H);
    float d = v - mu;
    float sq = wave_reduce_sum(d * d);
    if (lane == 0) r2[wave] = sq;
    __syncthreads();
    float var = (r2[0] + r2[1] + r2[2] + r2[3]) * (1.0f / H);
    out[(size_t)row * H + tid] = d * rsqrtf(var + 1e-5f) * gamma[tid] + beta[tid];
}

// ---------------------------------------------------------------------------
extern "C" void kernel_launch(void* const* d_in, const int* in_sizes, int n_in,
                              void* d_out, int out_size, void* d_ws, size_t ws_size,
                              hipStream_t stream) {
    const float* target_h = (const float*)d_in[0];
    const float* peer_h   = (const float*)d_in[1];
    const unsigned char* peer_mask = (const unsigned char*)d_in[2];
    const float* wq = (const float*)d_in[3];
    const float* bq = (const float*)d_in[4];
    const float* wk = (const float*)d_in[5];
    // bk (d_in[6]) is provably irrelevant: Q·bk is a per-(b,t) uniform logit
    // shift, invariant under top-k + softmax.
    const float* wv = (const float*)d_in[7];
    const float* bv = (const float*)d_in[8];
    const float* w1 = (const float*)d_in[9];
    const float* b1 = (const float*)d_in[10];
    const float* w2 = (const float*)d_in[11];
    const float* b2 = (const float*)d_in[12];
    const float* gamma = (const float*)d_in[13];
    const float* beta  = (const float*)d_in[14];
    float* out = (float*)d_out;

    char* ws = (char*)d_ws;
    size_t off = 0;
    auto wsa = [&](size_t bytes) -> void* {
        void* p = ws + off;
        off += (bytes + 255) & ~(size_t)255;
        return p;
    };
    int*   maskI  = (int*)wsa(B * N * sizeof(int));
    float* Wqk    = (float*)wsa((size_t)H * H * 4);
    float* cqk    = (float*)wsa((size_t)H * 4);
    float* Qk     = (float*)wsa((size_t)B * T * H * 4);
    float* logits = (float*)wsa((size_t)B * N * T * L * 4);
    float* u      = (float*)wsa((size_t)B * T * H * 4);
    float* sw     = (float*)wsa((size_t)B * T * 4);
    float* csy    = (float*)wsa((size_t)B * T * H * 4);
    float* h1     = (float*)wsa((size_t)B * T * H * 4);
    float* yv     = (float*)wsa((size_t)B * T * H * 4);

    prep_kernel<<<17, 256, 0, stream>>>(wq, wk, bq, peer_mask, Wqk, cqk, maskI);
    gemm_kernel<0, 0, 0><<<(B * T / 64) * 4, 256, 0, stream>>>(target_h, Wqk, cqk, nullptr, nullptr, Qk);
    logits_dot_kernel<<<B * N * 4, 256, 0, stream>>>(Qk, peer_h, maskI, logits);
    topk_gather_kernel<<<B * T, 256, 0, stream>>>(logits, peer_h, u, sw);
    gemm_kernel<0, 1, 1><<<(B * T / 64) * 4, 256, 0, stream>>>(u, wv, bv, sw, nullptr, csy);
    gemm_kernel<0, 1, 2><<<(B * T / 64) * 4, 256, 0, stream>>>(csy, w1, b1, nullptr, nullptr, h1);
    gemm_kernel<0, 1, 3><<<(B * T / 64) * 4, 256, 0, stream>>>(h1, w2, b2, nullptr, csy, yv);
    layernorm_kernel<<<B * T, 256, 0, stream>>>(yv, gamma, beta, out);
}